// Round 2
// baseline (139.140 us; speedup 1.0000x reference)
//
#include <hip/hip_runtime.h>
#include <math.h>
#include <float.h>

// LearnedRouter: B=4, S=4096, D=1024, N=256, TOPK=8
// Outputs (concat, fp32): token_repr[B,S,D], bank_indices[B,S], weights[B,S,N], topk_idx[B,S,8]

namespace {
constexpr int kB = 4, kS = 4096, kD = 1024, kN = 256, kK = 8;
constexpr float kScale = 0.03125f;   // 1/sqrt(1024)
constexpr float kNeg = -1e9f;
constexpr size_t kBankOff = (size_t)kB * kS * kD;            // 16777216
constexpr size_t kWOff    = kBankOff + (size_t)kB * kS;      // 16793600
constexpr size_t kTopkOff = kWOff + (size_t)kB * kS * kN;    // 20987904
}

// ---------------------------------------------------------------------------
// Kernel 1: R[n,d] = kScale * (dr @ Wq)[n,d];  bias[n] = kScale * (bq . dr[n])
// One block per n-row; 256 threads x one float4 output each; float4 Wq loads.
// 1024 waves total, pure-FMA floor ~4 us.
// ---------------------------------------------------------------------------
__global__ __launch_bounds__(256) void k_prep(const float* __restrict__ dr,
                                              const float* __restrict__ wq,
                                              const float* __restrict__ bq,
                                              float* __restrict__ R,
                                              float* __restrict__ bias) {
  const int n = blockIdx.x;
  const int t = threadIdx.x;
  const float4* wq4 = reinterpret_cast<const float4*>(wq);     // [1024][256] f4
  const float4* dr4 = reinterpret_cast<const float4*>(dr + (size_t)n * kD);
  float4 a0 = make_float4(0.f, 0.f, 0.f, 0.f);
  float4 a1 = a0, a2 = a0, a3 = a0;
#pragma unroll 8
  for (int e4 = 0; e4 < kD / 4; ++e4) {
    const float4 a = dr4[e4];
    const float4* w = wq4 + (size_t)(e4 * 4) * (kD / 4) + t;
    const float4 w0 = w[0];
    const float4 w1 = w[kD / 4];
    const float4 w2 = w[2 * (kD / 4)];
    const float4 w3 = w[3 * (kD / 4)];
    a0.x += a.x * w0.x; a0.y += a.x * w0.y; a0.z += a.x * w0.z; a0.w += a.x * w0.w;
    a1.x += a.y * w1.x; a1.y += a.y * w1.y; a1.z += a.y * w1.z; a1.w += a.y * w1.w;
    a2.x += a.z * w2.x; a2.y += a.z * w2.y; a2.z += a.z * w2.z; a2.w += a.z * w2.w;
    a3.x += a.w * w3.x; a3.y += a.w * w3.y; a3.z += a.w * w3.z; a3.w += a.w * w3.w;
  }
  float4 r;
  r.x = (a0.x + a1.x + a2.x + a3.x) * kScale;
  r.y = (a0.y + a1.y + a2.y + a3.y) * kScale;
  r.z = (a0.z + a1.z + a2.z + a3.z) * kScale;
  r.w = (a0.w + a1.w + a2.w + a3.w) * kScale;
  reinterpret_cast<float4*>(R)[(size_t)n * (kD / 4) + t] = r;

  if (t < 64) {  // wave 0: bias[n]
    const float4* b4 = reinterpret_cast<const float4*>(bq);
    float p = 0.f;
#pragma unroll
    for (int i = 0; i < 4; ++i) {
      const float4 bb = b4[t * 4 + i];
      const float4 dd = dr4[t * 4 + i];
      p += bb.x * dd.x + bb.y * dd.y + bb.z * dd.z + bb.w * dd.w;
    }
#pragma unroll
    for (int off = 32; off; off >>= 1) p += __shfl_xor(p, off);
    if (t == 0) bias[n] = p * kScale;
  }
}

// ---------------------------------------------------------------------------
// Kernel 2: one wave per token; 4096 blocks x 256 threads.
// Scores via 8 PARALLEL 8-lane-group dots (3-shfl reduce + 8 broadcasts),
// then per-lane-redundant dedup/top-k/softmax (static reg indexing), then
// coalesced writes. ss-gather: load-8-then-FMA per d-chunk (w[k]==0 kills
// filler rows, no branches).
// ---------------------------------------------------------------------------
__global__ __launch_bounds__(256, 4) void k_main(const float* __restrict__ ts,
                                                 const float* __restrict__ ss,
                                                 const int* __restrict__ t2s,
                                                 const float* __restrict__ R,
                                                 const float* __restrict__ bias,
                                                 const float* __restrict__ temp_p,
                                                 float* __restrict__ out) {
  const int lane = threadIdx.x & 63;
  const int wid = threadIdx.x >> 6;
  const int bid = blockIdx.x;
  // XCD-aware swizzle: XCD pair (2b,2b+1) owns batch b -> its set_states/R
  // stay L2-resident (2 MiB working set vs 4 MiB L2/XCD).
  const int xcd = bid & 7;
  const int b = xcd >> 1;
  const int s = ((bid >> 3) << 2) + wid + ((xcd & 1) << 11);
  const size_t row = (size_t)b * kS + s;

  const int g = lane >> 3;   // group 0..7 handles set slot g
  const int sub = lane & 7;  // lane-in-group

  // --- score phase: group g computes dot(ts_row, R[n_g]) ---
  int myraw = t2s[s * kK + g];
  int myn = myraw < 0 ? 0 : (myraw > kN - 1 ? kN - 1 : myraw);
  const float4* t4 = reinterpret_cast<const float4*>(ts) + row * (kD / 4);
  const float4* r4 = reinterpret_cast<const float4*>(R) + (size_t)myn * (kD / 4);
  float p0 = 0.f, p1 = 0.f, p2 = 0.f, p3 = 0.f;
#pragma unroll 8
  for (int i = 0; i < 32; i += 4) {
    const float4 tv0 = t4[sub + 8 * i];
    const float4 rv0 = r4[sub + 8 * i];
    const float4 tv1 = t4[sub + 8 * (i + 1)];
    const float4 rv1 = r4[sub + 8 * (i + 1)];
    const float4 tv2 = t4[sub + 8 * (i + 2)];
    const float4 rv2 = r4[sub + 8 * (i + 2)];
    const float4 tv3 = t4[sub + 8 * (i + 3)];
    const float4 rv3 = r4[sub + 8 * (i + 3)];
    p0 += tv0.x * rv0.x + tv0.y * rv0.y + tv0.z * rv0.z + tv0.w * rv0.w;
    p1 += tv1.x * rv1.x + tv1.y * rv1.y + tv1.z * rv1.z + tv1.w * rv1.w;
    p2 += tv2.x * rv2.x + tv2.y * rv2.y + tv2.z * rv2.z + tv2.w * rv2.w;
    p3 += tv3.x * rv3.x + tv3.y * rv3.y + tv3.z * rv3.z + tv3.w * rv3.w;
  }
  float a = (p0 + p1) + (p2 + p3);
  a += __shfl_xor(a, 1);
  a += __shfl_xor(a, 2);
  a += __shfl_xor(a, 4);
  a += bias[myn];

  // broadcast all 8 group scores to every lane
  float sc[kK];
#pragma unroll
  for (int k = 0; k < kK; ++k) sc[k] = __shfl(a, k * 8);

  int nraw[kK], nk[kK];
#pragma unroll
  for (int k = 0; k < kK; ++k) nraw[k] = t2s[s * kK + k];
#pragma unroll
  for (int k = 0; k < kK; ++k) {
    const int n = nraw[k];
    nk[k] = n < 0 ? 0 : (n > kN - 1 ? kN - 1 : n);
  }

  // validity + dedup (mask semantics of reference scatter-max)
  int validmask = 0;
#pragma unroll
  for (int k = 0; k < kK; ++k) {
    bool v = (nraw[k] >= 0);
#pragma unroll
    for (int j = 0; j < kK; ++j)
      if (j < k && nk[j] == nk[k]) v = false;
    if (v) validmask |= (1 << k);
  }
  const int cnt = __popc(validmask);

  // selection sort into 8 slots: key = (score desc, index asc); invalid -> -FLT_MAX
  float ssc[kK];
  int sidx[kK];
  int rem = 0xFF;
#pragma unroll
  for (int i = 0; i < kK; ++i) {
    float bs = -INFINITY;
    int bn = 0x7fffffff;
    int bk = 0;
#pragma unroll
    for (int k = 0; k < kK; ++k) {
      const bool avail = (rem >> k) & 1;
      const float v = ((validmask >> k) & 1) ? sc[k] : -FLT_MAX;
      if (avail && (v > bs || (v == bs && nk[k] < bn))) { bs = v; bn = nk[k]; bk = k; }
    }
    rem &= ~(1 << bk);
    ssc[i] = bs;
    sidx[i] = bn;
  }

  // filler slots (jax.lax.top_k tie-break on the NEG plateau: lowest unmasked
  // indices ascending)
  int fill = 0;
#pragma unroll
  for (int i = 0; i < kK; ++i) {
    if (i >= cnt) {
      bool moved = true;
      while (moved) {
        moved = false;
#pragma unroll
        for (int j = 0; j < kK; ++j)
          if (j < cnt && sidx[j] == fill) { ++fill; moved = true; }
      }
      sidx[i] = fill;
      ssc[i] = kNeg;
      ++fill;
    }
  }

  // softmax over kept entries; non-kept -> exact 0
  const float temp = fmaxf(temp_p[0], 0.5f);
  const float m = ssc[0];
  float w[kK];
  float denom = 0.f;
#pragma unroll
  for (int i = 0; i < kK; ++i) {
    const float e = (i < cnt) ? expf((ssc[i] - m) / temp) : 0.f;
    w[i] = e;
    denom += e;
  }
#pragma unroll
  for (int i = 0; i < kK; ++i) w[i] /= denom;

  // weights row [N]: float4 per lane, coalesced 1KB/wave
  {
    const int c0 = lane * 4;
    float4 wv = make_float4(0.f, 0.f, 0.f, 0.f);
#pragma unroll
    for (int k = 0; k < kK; ++k) {
      wv.x = (sidx[k] == c0    ) ? w[k] : wv.x;
      wv.y = (sidx[k] == c0 + 1) ? w[k] : wv.y;
      wv.z = (sidx[k] == c0 + 2) ? w[k] : wv.z;
      wv.w = (sidx[k] == c0 + 3) ? w[k] : wv.w;
    }
    reinterpret_cast<float4*>(out + kWOff)[row * (kN / 4) + lane] = wv;
  }

  // token_repr: per d-chunk, issue all 8 gathers then FMA (w==0 for fillers)
  {
    const float4* ssb = reinterpret_cast<const float4*>(ss) + (size_t)b * kN * (kD / 4);
    float4* o4 = reinterpret_cast<float4*>(out) + row * (kD / 4);
#pragma unroll
    for (int c = 0; c < 4; ++c) {
      float4 v0 = ssb[(size_t)sidx[0] * (kD / 4) + c * 64 + lane];
      float4 v1 = ssb[(size_t)sidx[1] * (kD / 4) + c * 64 + lane];
      float4 v2 = ssb[(size_t)sidx[2] * (kD / 4) + c * 64 + lane];
      float4 v3 = ssb[(size_t)sidx[3] * (kD / 4) + c * 64 + lane];
      float4 v4 = ssb[(size_t)sidx[4] * (kD / 4) + c * 64 + lane];
      float4 v5 = ssb[(size_t)sidx[5] * (kD / 4) + c * 64 + lane];
      float4 v6 = ssb[(size_t)sidx[6] * (kD / 4) + c * 64 + lane];
      float4 v7 = ssb[(size_t)sidx[7] * (kD / 4) + c * 64 + lane];
      float4 acc;
      acc.x = w[0] * v0.x + w[1] * v1.x + w[2] * v2.x + w[3] * v3.x
            + w[4] * v4.x + w[5] * v5.x + w[6] * v6.x + w[7] * v7.x;
      acc.y = w[0] * v0.y + w[1] * v1.y + w[2] * v2.y + w[3] * v3.y
            + w[4] * v4.y + w[5] * v5.y + w[6] * v6.y + w[7] * v7.y;
      acc.z = w[0] * v0.z + w[1] * v1.z + w[2] * v2.z + w[3] * v3.z
            + w[4] * v4.z + w[5] * v5.z + w[6] * v6.z + w[7] * v7.z;
      acc.w = w[0] * v0.w + w[1] * v1.w + w[2] * v2.w + w[3] * v3.w
            + w[4] * v4.w + w[5] * v5.w + w[6] * v6.w + w[7] * v7.w;
      o4[c * 64 + lane] = acc;
    }
  }

  // topk_idx (as float): lanes 0..7, register-select to avoid dynamic indexing
  if (lane < kK) {
    int v = 0;
#pragma unroll
    for (int k = 0; k < kK; ++k) v = (lane == k) ? sidx[k] : v;
    out[kTopkOff + row * kK + lane] = (float)v;
  }

  // bank_indices: argmax of weights, first-max tie-break
  if (lane == 0) {
    float wm = w[0];
    int bi = sidx[0];
#pragma unroll
    for (int i = 1; i < kK; ++i) {
      if (i < cnt) {
        if (w[i] > wm || (w[i] == wm && sidx[i] < bi)) { wm = w[i]; bi = sidx[i]; }
      }
    }
    out[kBankOff + row] = (float)bi;
  }
}

extern "C" void kernel_launch(void* const* d_in, const int* in_sizes, int n_in,
                              void* d_out, int out_size, void* d_ws, size_t ws_size,
                              hipStream_t stream) {
  const float* ts  = (const float*)d_in[0];   // token_states [4,4096,1024]
  const float* ss  = (const float*)d_in[1];   // set_states   [4,256,1024]
  const float* dr  = (const float*)d_in[2];   // desc_router  [256,1024]
  const int*   t2s = (const int*)  d_in[3];   // token_to_sets[4096,8]
  const float* wq  = (const float*)d_in[4];   // Wq [1024,1024]
  const float* bq  = (const float*)d_in[5];   // bq [1024]
  const float* tmp = (const float*)d_in[6];   // temperature [1]
  float* out = (float*)d_out;

  float* R    = (float*)d_ws;                 // 256*1024 f32 = 1 MiB
  float* bias = R + (size_t)kN * kD;          // 256 f32

  k_prep<<<kN, 256, 0, stream>>>(dr, wq, bq, R, bias);
  k_main<<<kB * kS / 4, 256, 0, stream>>>(ts, ss, t2s, R, bias, tmp, out);
}

// Round 3
// 71.076 us; speedup vs baseline: 1.9576x; 1.9576x over previous
//
#include <hip/hip_runtime.h>
#include <math.h>
#include <float.h>

// LearnedRouter: B=4, S=4096, D=1024, N=256, TOPK=8
// Outputs (concat, fp32): token_repr[B,S,D], bank_indices[B,S], weights[B,S,N], topk_idx[B,S,8]

namespace {
constexpr int kB = 4, kS = 4096, kD = 1024, kN = 256, kK = 8;
constexpr float kScale = 0.03125f;   // 1/sqrt(1024)
constexpr float kNeg = -1e9f;
constexpr float kLog2e = 1.4426950408889634f;
constexpr size_t kBankOff = (size_t)kB * kS * kD;            // 16777216
constexpr size_t kWOff    = kBankOff + (size_t)kB * kS;      // 16793600
constexpr size_t kTopkOff = kWOff + (size_t)kB * kS * kN;    // 20987904
constexpr int kEC = 16;          // e-chunks (K-split) in k_prep
constexpr int kEL = kD / kEC;    // 64 e per chunk
constexpr int kNT = kN / 8;      // 32 n-tiles of 8 rows
}

#if __has_builtin(__builtin_amdgcn_exp2f)
#define FAST_EXP2(x) __builtin_amdgcn_exp2f(x)
#else
#define FAST_EXP2(x) exp2f(x)
#endif
#if __has_builtin(__builtin_amdgcn_rcpf)
#define FAST_RCP(x) __builtin_amdgcn_rcpf(x)
#else
#define FAST_RCP(x) (1.0f / (x))
#endif

// ---------------------------------------------------------------------------
// k_prep: partial[ec][n][d] = sum_{e in chunk ec} dr[n,e] * Wq[e,d]
// Grid (32 n-tiles, 16 e-chunks) x 256 thr. Thread owns 8 n x 4 d (float4).
// dr loads are wave-uniform -> SMEM; Wq float4 coalesced. 2048 waves.
// Partials land in d_out's weights region (4M floats), overwritten later by
// k_main's weights write -- deterministic, stream-ordered.
// ---------------------------------------------------------------------------
__global__ __launch_bounds__(256) void k_prep(const float* __restrict__ dr,
                                              const float* __restrict__ wq,
                                              float* __restrict__ part) {
  const int nt = blockIdx.x, ec = blockIdx.y, t = threadIdx.x;
  const float4* wq4 = reinterpret_cast<const float4*>(wq);   // [e][256]
  float4 acc[8];
#pragma unroll
  for (int j = 0; j < 8; ++j) acc[j] = make_float4(0.f, 0.f, 0.f, 0.f);
  const int e0 = ec * kEL;
#pragma unroll 4
  for (int e = e0; e < e0 + kEL; ++e) {
    const float4 wv = wq4[(size_t)e * (kD / 4) + t];
#pragma unroll
    for (int j = 0; j < 8; ++j) {
      const float a = dr[(size_t)(nt * 8 + j) * kD + e];   // uniform -> s_load
      acc[j].x += a * wv.x; acc[j].y += a * wv.y;
      acc[j].z += a * wv.z; acc[j].w += a * wv.w;
    }
  }
  float4* p4 = reinterpret_cast<float4*>(part);
#pragma unroll
  for (int j = 0; j < 8; ++j)
    p4[((size_t)ec * kN + nt * 8 + j) * (kD / 4) + t] = acc[j];
}

// ---------------------------------------------------------------------------
// k_reduce: R[n][d] = kScale * sum_ec partial[ec][n][d];  bias[n] likewise.
// 256 blocks x 256 thr.
// ---------------------------------------------------------------------------
__global__ __launch_bounds__(256) void k_reduce(const float* __restrict__ part,
                                                const float* __restrict__ dr,
                                                const float* __restrict__ bq,
                                                float* __restrict__ R,
                                                float* __restrict__ bias) {
  const int n = blockIdx.x, t = threadIdx.x;
  const float4* p4 = reinterpret_cast<const float4*>(part);
  float4 a = make_float4(0.f, 0.f, 0.f, 0.f);
#pragma unroll
  for (int ec = 0; ec < kEC; ++ec) {
    const float4 p = p4[((size_t)ec * kN + n) * (kD / 4) + t];
    a.x += p.x; a.y += p.y; a.z += p.z; a.w += p.w;
  }
  a.x *= kScale; a.y *= kScale; a.z *= kScale; a.w *= kScale;
  reinterpret_cast<float4*>(R)[(size_t)n * (kD / 4) + t] = a;

  if (t < 64) {
    const float4* b4 = reinterpret_cast<const float4*>(bq);
    const float4* dr4 = reinterpret_cast<const float4*>(dr + (size_t)n * kD);
    float p = 0.f;
#pragma unroll
    for (int i = 0; i < 4; ++i) {
      const float4 bb = b4[t * 4 + i];
      const float4 dd = dr4[t * 4 + i];
      p += bb.x * dd.x + bb.y * dd.y + bb.z * dd.z + bb.w * dd.w;
    }
#pragma unroll
    for (int off = 32; off; off >>= 1) p += __shfl_xor(p, off);
    if (t == 0) bias[n] = p * kScale;
  }
}

// ---------------------------------------------------------------------------
// k_main: one wave per token. Scalarized control (readfirstlane) -> t2s via
// SMEM, dedup/fill in SALU. Coalesced full-wave fp32 dots, exp2/rcp softmax,
// Batcher-19 sort only for topk_idx, ss chunk-0 prefetched before the dots.
// ---------------------------------------------------------------------------
__global__ __launch_bounds__(256) void k_main(const float* __restrict__ ts,
                                              const float* __restrict__ ss,
                                              const int* __restrict__ t2s,
                                              const float* __restrict__ R,
                                              const float* __restrict__ bias,
                                              const float* __restrict__ temp_p,
                                              float* __restrict__ out) {
  const int lane = threadIdx.x & 63;
  const int wid = threadIdx.x >> 6;
  const int bid = blockIdx.x;
  // XCD pair (2b,2b+1) owns batch b -> ss[b] (1 MiB) + R (1 MiB) L2-resident.
  const int xcd = bid & 7;
  const int b = xcd >> 1;
  int s_ = ((bid >> 3) << 2) + wid + ((xcd & 1) << 11);
  const int s = __builtin_amdgcn_readfirstlane(s_);   // force wave-uniform
  const size_t row = (size_t)b * kS + s;

  // --- routing indices (SALU/SMEM) ---
  int nraw[kK], nk[kK];
#pragma unroll
  for (int k = 0; k < kK; ++k) {
    nraw[k] = t2s[s * kK + k];
    const int n = nraw[k];
    nk[k] = n < 0 ? 0 : (n > kN - 1 ? kN - 1 : n);
  }
  int validmask = 0;
#pragma unroll
  for (int k = 0; k < kK; ++k) {
    bool v = (nraw[k] >= 0);
#pragma unroll
    for (int j = 0; j < kK; ++j)
      if (j < k && nk[j] == nk[k]) v = false;
    validmask |= v ? (1 << k) : 0;
  }
  const int cnt = __popc(validmask);

  // --- prefetch ss chunk 0 (addresses need only nk) ---
  const float4* ssb = reinterpret_cast<const float4*>(ss) + (size_t)b * kN * (kD / 4);
  float4 s0[kK];
#pragma unroll
  for (int k = 0; k < kK; ++k) s0[k] = ssb[(size_t)nk[k] * (kD / 4) + lane];

  // --- token row (4 coalesced 4KB loads) ---
  const float4* t4 = reinterpret_cast<const float4*>(ts) + row * (kD / 4);
  const float4 tv0 = t4[lane];
  const float4 tv1 = t4[64 + lane];
  const float4 tv2 = t4[128 + lane];
  const float4 tv3 = t4[192 + lane];

  // --- 8 full-wave dots (partials), then independent butterfly reduces ---
  float pk[kK];
#pragma unroll
  for (int k = 0; k < kK; ++k) {
    const float4* r4 = reinterpret_cast<const float4*>(R) + (size_t)nk[k] * (kD / 4);
    const float4 r0 = r4[lane];
    const float4 r1 = r4[64 + lane];
    const float4 r2 = r4[128 + lane];
    const float4 r3 = r4[192 + lane];
    float a = tv0.x * r0.x + tv0.y * r0.y + tv0.z * r0.z + tv0.w * r0.w;
    a += tv1.x * r1.x + tv1.y * r1.y + tv1.z * r1.z + tv1.w * r1.w;
    a += tv2.x * r2.x + tv2.y * r2.y + tv2.z * r2.z + tv2.w * r2.w;
    a += tv3.x * r3.x + tv3.y * r3.y + tv3.z * r3.z + tv3.w * r3.w;
    pk[k] = a;
  }
#pragma unroll
  for (int k = 0; k < kK; ++k) {
    float a = pk[k];
    a += __shfl_xor(a, 1);
    a += __shfl_xor(a, 2);
    a += __shfl_xor(a, 4);
    a += __shfl_xor(a, 8);
    a += __shfl_xor(a, 16);
    a += __shfl_xor(a, 32);
    pk[k] = a + bias[nk[k]];
  }

  // --- softmax over valid slots (no sort needed) ---
  float mx = -INFINITY;
#pragma unroll
  for (int k = 0; k < kK; ++k)
    mx = fmaxf(mx, ((validmask >> k) & 1) ? pk[k] : -INFINITY);
  const float it = kLog2e * FAST_RCP(fmaxf(temp_p[0], 0.5f));
  float w[kK];
  float denom = 0.f;
#pragma unroll
  for (int k = 0; k < kK; ++k) {
    const float e = ((validmask >> k) & 1) ? FAST_EXP2((pk[k] - mx) * it) : 0.f;
    w[k] = e;
    denom += e;
  }
  const float rd = FAST_RCP(denom);
#pragma unroll
  for (int k = 0; k < kK; ++k) w[k] *= rd;

  // --- token_repr: chunk 0 from prefetch, chunks 1-3 load->fma->store ---
  float4* o4 = reinterpret_cast<float4*>(out) + row * (kD / 4);
  {
    float4 acc = make_float4(0.f, 0.f, 0.f, 0.f);
#pragma unroll
    for (int k = 0; k < kK; ++k) {
      acc.x += w[k] * s0[k].x; acc.y += w[k] * s0[k].y;
      acc.z += w[k] * s0[k].z; acc.w += w[k] * s0[k].w;
    }
    o4[lane] = acc;
  }
#pragma unroll
  for (int c = 1; c < 4; ++c) {
    float4 v[kK];
#pragma unroll
    for (int k = 0; k < kK; ++k)
      v[k] = ssb[(size_t)nk[k] * (kD / 4) + c * 64 + lane];
    float4 acc = make_float4(0.f, 0.f, 0.f, 0.f);
#pragma unroll
    for (int k = 0; k < kK; ++k) {
      acc.x += w[k] * v[k].x; acc.y += w[k] * v[k].y;
      acc.z += w[k] * v[k].z; acc.w += w[k] * v[k].w;
    }
    o4[c * 64 + lane] = acc;
  }

  // --- weights row [N]: float4 per lane (guard: only valid slots write) ---
  {
    const int c0 = lane * 4;
    float4 wv = make_float4(0.f, 0.f, 0.f, 0.f);
#pragma unroll
    for (int k = 0; k < kK; ++k) {
      const bool vb = (validmask >> k) & 1;
      wv.x = (vb && nk[k] == c0    ) ? w[k] : wv.x;
      wv.y = (vb && nk[k] == c0 + 1) ? w[k] : wv.y;
      wv.z = (vb && nk[k] == c0 + 2) ? w[k] : wv.z;
      wv.w = (vb && nk[k] == c0 + 3) ? w[k] : wv.w;
    }
    reinterpret_cast<float4*>(out + kWOff)[row * (kN / 4) + lane] = wv;
  }

  // --- fill indices: smallest absent set ids (SALU, 4x u64 presence mask) ---
  unsigned long long pm0 = 0, pm1 = 0, pm2 = 0, pm3 = 0;
#pragma unroll
  for (int k = 0; k < kK; ++k) {
    const bool v = (validmask >> k) & 1;
    const unsigned long long bit = 1ull << (nk[k] & 63);
    const int wd = nk[k] >> 6;
    pm0 |= (v && wd == 0) ? bit : 0ull;
    pm1 |= (v && wd == 1) ? bit : 0ull;
    pm2 |= (v && wd == 2) ? bit : 0ull;
    pm3 |= (v && wd == 3) ? bit : 0ull;
  }
  int seq[kK];
#pragma unroll
  for (int i = 0; i < kK; ++i) {
    const unsigned long long i0 = ~pm0, i1 = ~pm1, i2 = ~pm2, i3 = ~pm3;
    const int c = i0 ? (__ffsll(i0) - 1)
                     : (i1 ? 64 + (__ffsll(i1) - 1)
                           : (i2 ? 128 + (__ffsll(i2) - 1)
                                 : 192 + (__ffsll(i3) - 1)));
    seq[i] = c;
    const unsigned long long b2 = 1ull << (c & 63);
    const int wd = c >> 6;
    pm0 |= (wd == 0) ? b2 : 0ull;
    pm1 |= (wd == 1) ? b2 : 0ull;
    pm2 |= (wd == 2) ? b2 : 0ull;
    pm3 |= (wd == 3) ? b2 : 0ull;
  }

  // --- merge fills into slots, then Batcher-19 sort (desc score, asc idx) ---
  float fs[kK];
  int fi[kK];
#pragma unroll
  for (int k = 0; k < kK; ++k) {
    const bool v = (validmask >> k) & 1;
    const int jk = __popc((~validmask) & ((1 << k) - 1));
    int fv = seq[0];
#pragma unroll
    for (int j = 1; j < kK; ++j) fv = (jk == j) ? seq[j] : fv;
    fs[k] = v ? pk[k] : kNeg;
    fi[k] = v ? nk[k] : fv;
  }
#define CE(A, B)                                                        \
  {                                                                     \
    const bool sw = (fs[B] > fs[A]) || (fs[B] == fs[A] && fi[B] < fi[A]); \
    const float fa = fs[A], fb = fs[B];                                 \
    const int ia = fi[A], ib = fi[B];                                   \
    fs[A] = sw ? fb : fa; fs[B] = sw ? fa : fb;                         \
    fi[A] = sw ? ib : ia; fi[B] = sw ? ia : ib;                         \
  }
  CE(0,1) CE(2,3) CE(4,5) CE(6,7)
  CE(0,2) CE(1,3) CE(4,6) CE(5,7)
  CE(1,2) CE(5,6)
  CE(0,4) CE(1,5) CE(2,6) CE(3,7)
  CE(2,4) CE(3,5)
  CE(1,2) CE(3,4) CE(5,6)
#undef CE

  // --- topk_idx (lanes 0-7) + bank_indices (sorted slot 0) ---
  if (lane < kK) {
    int v = fi[0];
#pragma unroll
    for (int k = 1; k < kK; ++k) v = (lane == k) ? fi[k] : v;
    out[kTopkOff + row * kK + lane] = (float)v;
  }
  if (lane == 0) out[kBankOff + row] = (float)fi[0];
}

extern "C" void kernel_launch(void* const* d_in, const int* in_sizes, int n_in,
                              void* d_out, int out_size, void* d_ws, size_t ws_size,
                              hipStream_t stream) {
  const float* ts  = (const float*)d_in[0];   // token_states [4,4096,1024]
  const float* ss  = (const float*)d_in[1];   // set_states   [4,256,1024]
  const float* dr  = (const float*)d_in[2];   // desc_router  [256,1024]
  const int*   t2s = (const int*)  d_in[3];   // token_to_sets[4096,8]
  const float* wq  = (const float*)d_in[4];   // Wq [1024,1024]
  const float* bq  = (const float*)d_in[5];   // bq [1024]
  const float* tmp = (const float*)d_in[6];   // temperature [1]
  float* out = (float*)d_out;

  float* R    = (float*)d_ws;                 // 256*1024 f32 = 1 MiB
  float* bias = R + (size_t)kN * kD;          // 256 f32
  float* part = out + kWOff;                  // 16 MiB partials, overwritten by
                                              // k_main's weights write later

  k_prep<<<dim3(kNT, kEC), 256, 0, stream>>>(dr, wq, part);
  k_reduce<<<kN, 256, 0, stream>>>(part, dr, bq, R, bias);
  k_main<<<kB * kS / 4, 256, 0, stream>>>(ts, ss, t2s, R, bias, tmp, out);
}